// Round 16
// baseline (192.495 us; speedup 1.0000x reference)
//
#include <hip/hip_runtime.h>
#include <math.h>

#define DIMC 192
#define INNER 768
#define NEXP 8
#define NB 4
#define HH 64
#define WW 64
#define PPI 4096
#define NPIX 16384
#define MAXROWS 33792   // 264 * 128

typedef __attribute__((ext_vector_type(8))) short bf16x8;
typedef __attribute__((ext_vector_type(4))) float f32x4;

static __device__ __forceinline__ float bf2f(short s) {
  union { unsigned int u; float f; } v;
  v.u = ((unsigned int)(unsigned short)s) << 16;
  return v.f;
}
static __device__ __forceinline__ float bfLO(unsigned int u) {
  union { unsigned int u; float f; } v; v.u = u << 16; return v.f;
}
static __device__ __forceinline__ float bfHI(unsigned int u) {
  union { unsigned int u; float f; } v; v.u = u & 0xffff0000u; return v.f;
}
static __device__ __forceinline__ short f2bf(float f) {
  union { float f; unsigned int u; } v; v.f = f;
  unsigned int r = v.u + 0x7fffu + ((v.u >> 16) & 1u);
  return (short)(r >> 16);
}
static __device__ __forceinline__ unsigned int pk2(float a, float b) {
  return (unsigned int)(unsigned short)f2bf(a)
       | ((unsigned int)(unsigned short)f2bf(b) << 16);
}
static __device__ __forceinline__ void gl2lds16(const void* g, void* l) {
  __builtin_amdgcn_global_load_lds(
      (const __attribute__((address_space(1))) void*)g,
      (__attribute__((address_space(3))) void*)l, 16, 0, 0);
}

// ==== merged init: gate+LN | w1-fold | w2-cast | dwT transpose ===============
// bid [0,256): gate (1 chunk of 64 px each); [256,6400): w1p/b1p;
// [6400,7552): w2b; [7552,7768): dwT
__global__ __launch_bounds__(256) void k_init(const float* __restrict__ x,
                                              const float* __restrict__ wg,
                                              const float* __restrict__ bg,
                                              const float* __restrict__ w1,
                                              const float* __restrict__ b1,
                                              const float* __restrict__ lng,
                                              const float* __restrict__ lnb,
                                              const float* __restrict__ w2,
                                              const float* __restrict__ dw,
                                              short* __restrict__ nx,
                                              int* __restrict__ e01,
                                              float2* __restrict__ w01,
                                              int* __restrict__ cnt,
                                              short* __restrict__ w1p,
                                              float* __restrict__ b1p,
                                              short* __restrict__ w2b,
                                              short* __restrict__ dwT) {
  __shared__ float swg[NEXP][DIMC];
  __shared__ float sbg[NEXP];
  __shared__ float red[10][4][64];
  __shared__ float smr[2][64];
  __shared__ float part[4];
  const int bid = blockIdx.x;
  const int t = threadIdx.x;
  if (bid < 256) {
    // ---- gate + layernorm for 64 pixels ----
    const int gb = bid;
    for (int k = t; k < NEXP*DIMC; k += 256) swg[k/DIMC][k%DIMC] = wg[k];
    if (t < NEXP) sbg[t] = bg[t];
    __syncthreads();
    const int n0 = gb * 64;
    const int b = n0 >> 12;
    const int p0 = n0 & 4095;
    const int l = t & 63, w = t >> 6;
    const float* xp = x + (size_t)b*DIMC*PPI + p0 + l;
    float xr[48];
    float sum = 0.f, ssq = 0.f;
    float lg[NEXP] = {0,0,0,0,0,0,0,0};
    #pragma unroll
    for (int k = 0; k < 48; ++k) {
      const int c = w*48 + k;
      float xv = xp[(size_t)c*PPI];
      xr[k] = xv;
      sum += xv; ssq += xv*xv;
      #pragma unroll
      for (int e = 0; e < NEXP; ++e) lg[e] += xv * swg[e][c];
    }
    red[0][w][l] = sum;
    red[1][w][l] = ssq;
    #pragma unroll
    for (int e = 0; e < NEXP; ++e) red[2+e][w][l] = lg[e];
    __syncthreads();
    if (t < 64) {
      float ts = red[0][0][l] + red[0][1][l] + red[0][2][l] + red[0][3][l];
      float tq = red[1][0][l] + red[1][1][l] + red[1][2][l] + red[1][3][l];
      float lgt[NEXP];
      #pragma unroll
      for (int e = 0; e < NEXP; ++e)
        lgt[e] = red[2+e][0][l] + red[2+e][1][l] + red[2+e][2][l] + red[2+e][3][l] + sbg[e];
      const float mean = ts * (1.0f/DIMC);
      const float var  = tq * (1.0f/DIMC) - mean*mean;
      const float rstd = rsqrtf(var + 1e-5f);
      smr[0][l] = mean; smr[1][l] = rstd;
      int e0 = 0; float l0 = lgt[0];
      #pragma unroll
      for (int e = 1; e < NEXP; ++e) if (lgt[e] > l0) { l0 = lgt[e]; e0 = e; }
      int e1 = -1; float l1 = -1e30f;
      #pragma unroll
      for (int e = 0; e < NEXP; ++e) if (e != e0 && lgt[e] > l1) { l1 = lgt[e]; e1 = e; }
      const float ex = expf(l1 - l0);
      const float w0 = 1.0f/(1.0f + ex);
      const float w1v = ex * w0;
      e01[n0 + l] = e0 | (e1 << 8);
      w01[n0 + l] = make_float2(w0, w1v);
      #pragma unroll
      for (int e = 0; e < NEXP; ++e) {
        unsigned long long m = __ballot(e0 == e || e1 == e);
        if (l == 0) cnt[e*256 + gb] = (int)__popcll(m);
      }
    }
    __syncthreads();
    const float mean = smr[0][l], rstd = smr[1][l];
    short* nrow = nx + (size_t)(n0 + l)*DIMC + w*48;
    #pragma unroll
    for (int q = 0; q < 6; ++q) {
      bf16x8 v;
      #pragma unroll
      for (int j = 0; j < 8; ++j)
        v[j] = f2bf((xr[q*8 + j] - mean) * rstd);
      *(bf16x8*)(nrow + q*8) = v;
    }
  } else if (bid < 6400) {
    // ---- w1 fold ----
    const int r = bid - 256;
    const int e = r / 768, i = r - e*768;
    const size_t base = ((size_t)e*INNER + i)*DIMC;
    float rr = 0.f;
    if (t < DIMC) {
      const float w = w1[base + t];
      w1p[base + t] = f2bf(w * lng[e*DIMC + t]);
      rr = w * lnb[e*DIMC + t];
    }
    #pragma unroll
    for (int off = 32; off >= 1; off >>= 1) rr += __shfl_down(rr, off);
    const int lane = t & 63, wv = t >> 6;
    if (lane == 0) part[wv] = rr;
    __syncthreads();
    if (t == 0)
      b1p[e*INNER + i] = b1[e*INNER + i] + part[0] + part[1] + part[2];
  } else if (bid < 7552) {
    // ---- w2 cast ----
    const int n = NEXP*DIMC*INNER;
    int idx = ((bid - 6400)*256 + t)*4;
    if (idx + 3 < n) {
      float4 v = *(const float4*)(w2 + idx);
      short4 o; o.x = f2bf(v.x); o.y = f2bf(v.y); o.z = f2bf(v.z); o.w = f2bf(v.w);
      *(short4*)(w2b + idx) = o;
    } else {
      for (int k = idx; k < n; ++k) w2b[k] = f2bf(w2[k]);
    }
  } else {
    // ---- dwT transpose ----
    const int r = bid - 7552;                 // ((e*9)+q)*3 + cb
    const int cb = r % 3, qq = (r/3) % 9, e = r / 27;
    const int c = cb*256 + t;
    dwT[((size_t)e*9 + qq)*INNER + c] = f2bf(dw[((size_t)e*INNER + c)*9 + qq]);
  }
}

// -- routing: per-block redundant 256-chunk scan of cnt -> slots/pix/seg ------
__global__ __launch_bounds__(256) void k_route3(const int* __restrict__ e01,
                                                const int* __restrict__ cnt,
                                                int* __restrict__ j0a,
                                                int* __restrict__ j1a,
                                                int* __restrict__ pix,
                                                int* __restrict__ seg) {
  __shared__ int wc[NEXP][4];
  __shared__ int sOff[NEXP];    // exclusive chunk-prefix at chunk 4*bx
  __shared__ int sTot[NEXP];    // per-expert totals
  __shared__ int sSt[NEXP];     // segment starts
  const int t = threadIdx.x;
  const int bx = blockIdx.x;
  const int lane = t & 63, wv = t >> 6;
  const int n = bx*256 + t;
  const int ee = e01[n];
  const int e0 = ee & 0xff, e1 = (ee >> 8) & 0xff;
  unsigned long long masks[NEXP];
  #pragma unroll
  for (int e = 0; e < NEXP; ++e) {
    unsigned long long m = __ballot(e0 == e || e1 == e);
    if (lane == 0) wc[e][wv] = __popcll(m);
    masks[e] = m;
  }
  // wave wv scans experts 2wv, 2wv+1 over 256 chunks (4 x 64 with carry)
  #pragma unroll
  for (int s = 0; s < 2; ++s) {
    const int e = wv*2 + s;
    int carry = 0;
    #pragma unroll
    for (int q4 = 0; q4 < 4; ++q4) {
      const int v = cnt[e*256 + q4*64 + lane];
      int sc = v;
      #pragma unroll
      for (int d = 1; d < 64; d <<= 1) {
        int u = __shfl_up(sc, d);
        if (lane >= d) sc += u;
      }
      if (q4*64 + lane == (bx << 2)) sOff[e] = carry + sc - v;
      carry += __shfl(sc, 63);
    }
    if (lane == 0) sTot[e] = carry;
  }
  __syncthreads();
  if (t == 0) {
    int run = 0;
    #pragma unroll
    for (int q = 0; q < NEXP; ++q) {
      const int m = sTot[q];
      const int pad = (m + 127) & ~127;
      sSt[q] = run;
      if (bx == 0) {
        seg[q*3 + 0] = run;
        seg[q*3 + 1] = m;
        seg[q*3 + 2] = run + pad;
      }
      run += pad;
    }
    if (bx == 0) seg[24] = run;
  }
  __syncthreads();
  int j0 = 0, j1 = 0;
  #pragma unroll
  for (int e = 0; e < NEXP; ++e) {
    int base = sSt[e] + sOff[e];
    #pragma unroll
    for (int w = 0; w < 4; ++w) if (w < wv) base += wc[e][w];
    int rank = __popcll(masks[e] & ((1ull << lane) - 1ull));
    bool sel = (e0 == e || e1 == e);
    int j = base + rank;
    if (sel) pix[j] = n;
    if (e == e0) j0 = j;
    if (e == e1) j1 = j;
  }
  j0a[n] = j0; j1a[n] = j1;
}

// ------- up-projection GEMM: 256n x 128i tile, 512 threads (8 waves),
// ------- BK=64, XOR-swizzled LDS; epilogue LDS transpose -> hT[n][768] -------
__global__ __launch_bounds__(512) void k_up(const short* __restrict__ w1p,
                                            const float* __restrict__ b1p,
                                            const short* __restrict__ nx,
                                            short* __restrict__ hbuf, int eb) {
  __shared__ alignas(16) short smemU[256*136];   // GEMM As|Bs (48KB); TT (69.6KB)
  short* As = smemU;                              // [128][64sw]
  short* Bs = smemU + 128*64;                     // [256][64sw]
  const int el = blockIdx.z;
  const int e = eb + el;
  const short* A = w1p + (size_t)e*INNER*DIMC;
  short* H = hbuf + (size_t)el*NPIX*INNER;        // hT layout [n][768]
  const int n0 = blockIdx.x << 8;                 // 256 px
  const int i0 = blockIdx.y << 7;                 // 128 inner
  const int t = threadIdx.x;
  const int wv = t >> 6, lane = t & 63;
  const int wm = (wv & 1) << 6;                   // i-offset of wave
  const int wn = (wv >> 1) << 6;                  // n-offset of wave
  const int r15 = lane & 15, kg = lane >> 4;
  f32x4 acc[4][4] = {};
  for (int k0 = 0; k0 < DIMC; k0 += 64) {
    __syncthreads();
    #pragma unroll
    for (int q = 0; q < 2; ++q) {                 // A: 128 rows x 128B
      const int c = q*512 + t;
      const int row = c >> 3;
      const int kb = ((c & 7) << 4) ^ ((row & 7) << 4);
      gl2lds16(A + (size_t)(i0 + row)*DIMC + k0 + (kb >> 1), (char*)As + c*16);
    }
    #pragma unroll
    for (int q = 0; q < 4; ++q) {                 // B: 256 rows x 128B
      const int c = q*512 + t;
      const int row = c >> 3;
      const int kb = ((c & 7) << 4) ^ ((row & 7) << 4);
      gl2lds16(nx + (size_t)(n0 + row)*DIMC + k0 + (kb >> 1), (char*)Bs + c*16);
    }
    __syncthreads();
    #pragma unroll
    for (int ks = 0; ks < 2; ++ks) {
      bf16x8 af[4], bfr[4];
      #pragma unroll
      for (int mf = 0; mf < 4; ++mf) {
        const int row = wm + mf*16 + r15;
        const int kb = (ks*64 + kg*16) ^ ((row & 7) << 4);
        af[mf] = *(const bf16x8*)((const char*)As + row*128 + kb);
      }
      #pragma unroll
      for (int nf = 0; nf < 4; ++nf) {
        const int row = wn + nf*16 + r15;
        const int kb = (ks*64 + kg*16) ^ ((row & 7) << 4);
        bfr[nf] = *(const bf16x8*)((const char*)Bs + row*128 + kb);
      }
      #pragma unroll
      for (int mf = 0; mf < 4; ++mf)
        #pragma unroll
        for (int nf = 0; nf < 4; ++nf)
          acc[mf][nf] = __builtin_amdgcn_mfma_f32_16x16x32_bf16(af[mf], bfr[nf], acc[mf][nf], 0, 0, 0);
    }
  }
  // epilogue: acc(+bias) -> TT[n_l 256][i_l 128] (stride 136 shorts)
  __syncthreads();
  unsigned int* TT32 = (unsigned int*)smemU;
  const float* b1e = b1p + e*INNER + i0;
  #pragma unroll
  for (int mf = 0; mf < 4; ++mf) {
    const int ib = wm + mf*16 + (kg << 2);
    float bias[4];
    #pragma unroll
    for (int r = 0; r < 4; ++r) bias[r] = b1e[ib + r];
    #pragma unroll
    for (int nf = 0; nf < 4; ++nf) {
      const int nl = wn + nf*16 + r15;
      TT32[nl*68 + (ib >> 1)]     = pk2(acc[mf][nf][0] + bias[0], acc[mf][nf][1] + bias[1]);
      TT32[nl*68 + (ib >> 1) + 1] = pk2(acc[mf][nf][2] + bias[2], acc[mf][nf][3] + bias[3]);
    }
  }
  __syncthreads();
  const short* TT = smemU;
  #pragma unroll
  for (int s = 0; s < 8; ++s) {
    const int idx = (s << 9) + t;
    const int nl = idx >> 4, cg = idx & 15;
    bf16x8 v = *(const bf16x8*)(TT + nl*136 + cg*8);
    *(bf16x8*)(H + (size_t)(n0 + nl)*INNER + i0 + cg*8) = v;
  }
}

// ------- sparse depthwise 3x3 + GELU; thread = 4 slots x 4 channels ----------
// bf16 packed weights (9x8B regs); pad slots write zeros
__global__ __launch_bounds__(256) void k_dws(const short* __restrict__ hbuf,
                                             const short* __restrict__ dwT,
                                             const float* __restrict__ bdw,
                                             const int* __restrict__ pix,
                                             const int* __restrict__ seg,
                                             short* __restrict__ gTc,
                                             int eb, int ne) {
  const int j0 = blockIdx.x << 4;     // 16 slots per block (16 | 128 -> one expert)
  if (j0 >= seg[24]) return;
  int e = 0;
  #pragma unroll
  for (int q = 0; q < NEXP; ++q)
    if (j0 >= seg[q*3] && j0 < seg[q*3+2]) e = q;
  if (e < eb || e >= eb + ne) return;
  const int jend = seg[e*3] + seg[e*3+1];
  const int t = threadIdx.x;
  const int cq = t & 63;              // 64 ch-quads = 256 channels
  const int sq = t >> 6;              // 4 slot-quads
  const int ch = (blockIdx.y << 8) + (cq << 2);
  const short* hb = hbuf + (size_t)(e - eb)*NPIX*INNER;
  uint2 wq[9];
  #pragma unroll
  for (int q = 0; q < 9; ++q)
    wq[q] = *(const uint2*)(dwT + ((size_t)e*9 + q)*INNER + ch);
  const float4 bias = *(const float4*)(bdw + (size_t)e*INNER + ch);
  #pragma unroll
  for (int s = 0; s < 4; ++s) {
    const int j = j0 + (sq << 2) + s;
    if (j >= jend) {                  // padding slot: zero
      uint2 z; z.x = 0u; z.y = 0u;
      *(uint2*)(gTc + (size_t)j*INNER + ch) = z;
      continue;
    }
    const int n = pix[j];
    const int p = n & 4095, y = p >> 6, x = p & 63;
    uint2 v[9];
    #pragma unroll
    for (int dy = -1; dy <= 1; ++dy)
      #pragma unroll
      for (int dx = -1; dx <= 1; ++dx) {
        uint2 z; z.x = 0u; z.y = 0u;
        if ((unsigned)(y + dy) < 64u && (unsigned)(x + dx) < 64u)
          z = *(const uint2*)(hb + (size_t)(n + dy*64 + dx)*INNER + ch);
        v[(dy+1)*3 + dx + 1] = z;
      }
    float a0 = bias.x, a1 = bias.y, a2 = bias.z, a3 = bias.w;
    #pragma unroll
    for (int q = 0; q < 9; ++q) {
      a0 += bfLO(wq[q].x) * bfLO(v[q].x);
      a1 += bfHI(wq[q].x) * bfHI(v[q].x);
      a2 += bfLO(wq[q].y) * bfLO(v[q].y);
      a3 += bfHI(wq[q].y) * bfHI(v[q].y);
    }
    const float g0 = 0.5f*a0*(1.0f + erff(a0*0.70710678118654752f));
    const float g1 = 0.5f*a1*(1.0f + erff(a1*0.70710678118654752f));
    const float g2 = 0.5f*a2*(1.0f + erff(a2*0.70710678118654752f));
    const float g3 = 0.5f*a3*(1.0f + erff(a3*0.70710678118654752f));
    uint2 o; o.x = pk2(g0, g1); o.y = pk2(g2, g3);
    *(uint2*)(gTc + (size_t)j*INNER + ch) = o;
  }
}

// ------- down-projection GEMM: 128j x 64c tile, BK=64, swizzled LDS ----------
__global__ __launch_bounds__(256) void k_down(const short* __restrict__ w2b,
                                              const float* __restrict__ b2,
                                              const short* __restrict__ gTc,
                                              const int* __restrict__ seg,
                                              float* __restrict__ Oc) {
  __shared__ alignas(16) short As[64*64];    // [c][k64], XOR-swizzled
  __shared__ alignas(16) short Bs[128*64];   // [j][k64], XOR-swizzled
  __shared__ float sb2[64];
  const int j0g = blockIdx.x << 7;
  if (j0g >= seg[24]) return;
  int e = 0;
  #pragma unroll
  for (int q = 0; q < NEXP; ++q)
    if (j0g >= seg[q*3] && j0g < seg[q*3+2]) e = q;
  const int c0 = blockIdx.y << 6;
  const short* A = w2b + (size_t)e*DIMC*INNER;
  const short* B = gTc + (size_t)j0g*INNER;
  const int t = threadIdx.x;
  const int wv = t >> 6, lane = t & 63;
  const int wc_ = (wv & 1) << 5;   // c-offset of wave
  const int wj  = (wv >> 1) << 6;  // j-offset of wave
  const int r15 = lane & 15, kg = lane >> 4;
  if (t < 64) sb2[t] = b2[e*DIMC + c0 + t];
  f32x4 acc[2][4] = {};
  for (int k0 = 0; k0 < INNER; k0 += 64) {
    __syncthreads();
    #pragma unroll
    for (int q = 0; q < 2; ++q) {              // A: 64 rows x 128B
      const int c = q*256 + t;
      const int row = c >> 3;
      const int kb = ((c & 7) << 4) ^ ((row & 7) << 4);
      gl2lds16(A + (size_t)(c0 + row)*INNER + k0 + (kb >> 1), (char*)As + c*16);
    }
    #pragma unroll
    for (int q = 0; q < 4; ++q) {              // B: 128 rows x 128B
      const int c = q*256 + t;
      const int row = c >> 3;
      const int kb = ((c & 7) << 4) ^ ((row & 7) << 4);
      gl2lds16(B + (size_t)row*INNER + k0 + (kb >> 1), (char*)Bs + c*16);
    }
    __syncthreads();
    #pragma unroll
    for (int ks = 0; ks < 2; ++ks) {
      bf16x8 af[2], bfr[4];
      #pragma unroll
      for (int mf = 0; mf < 2; ++mf) {
        const int row = wc_ + mf*16 + r15;
        const int kb = (ks*64 + kg*16) ^ ((row & 7) << 4);
        af[mf] = *(const bf16x8*)((const char*)As + row*128 + kb);
      }
      #pragma unroll
      for (int nf = 0; nf < 4; ++nf) {
        const int row = wj + nf*16 + r15;
        const int kb = (ks*64 + kg*16) ^ ((row & 7) << 4);
        bfr[nf] = *(const bf16x8*)((const char*)Bs + row*128 + kb);
      }
      #pragma unroll
      for (int mf = 0; mf < 2; ++mf)
        #pragma unroll
        for (int nf = 0; nf < 4; ++nf)
          acc[mf][nf] = __builtin_amdgcn_mfma_f32_16x16x32_bf16(af[mf], bfr[nf], acc[mf][nf], 0, 0, 0);
    }
  }
  #pragma unroll
  for (int mf = 0; mf < 2; ++mf) {
    const int ccl = wc_ + mf*16 + (kg << 2);
    #pragma unroll
    for (int nf = 0; nf < 4; ++nf) {
      const int jj = j0g + wj + nf*16 + r15;
      float4 v;
      v.x = acc[mf][nf][0] + sb2[ccl + 0];
      v.y = acc[mf][nf][1] + sb2[ccl + 1];
      v.z = acc[mf][nf][2] + sb2[ccl + 2];
      v.w = acc[mf][nf][3] + sb2[ccl + 3];
      *(float4*)(Oc + (size_t)jj*DIMC + c0 + ccl) = v;
    }
  }
}

// ---------------- final gather: out = w0*Oc[j0] + w1*Oc[j1] ------------------
__global__ __launch_bounds__(256) void k_gather(const float* __restrict__ Oc,
                                                const int* __restrict__ j0a,
                                                const int* __restrict__ j1a,
                                                const float2* __restrict__ w01,
                                                float* __restrict__ out) {
  const int t = threadIdx.x;
  const int n = blockIdx.x*256 + t;
  const int b = n >> 12, p = n & 4095;
  const int j0 = j0a[n], j1 = j1a[n];
  const float2 w = w01[n];
  const float4* r0 = (const float4*)(Oc + (size_t)j0*DIMC);
  const float4* r1 = (const float4*)(Oc + (size_t)j1*DIMC);
  float* ob = out + (size_t)b*DIMC*PPI + p;
  for (int cq = 0; cq < 48; ++cq) {
    float4 a = r0[cq], c = r1[cq];
    ob[(size_t)(cq*4 + 0)*PPI] = w.x*a.x + w.y*c.x;
    ob[(size_t)(cq*4 + 1)*PPI] = w.x*a.y + w.y*c.y;
    ob[(size_t)(cq*4 + 2)*PPI] = w.x*a.z + w.y*c.z;
    ob[(size_t)(cq*4 + 3)*PPI] = w.x*a.w + w.y*c.w;
  }
}

extern "C" void kernel_launch(void* const* d_in, const int* in_sizes, int n_in,
                              void* d_out, int out_size, void* d_ws, size_t ws_size,
                              hipStream_t stream) {
  (void)in_sizes; (void)n_in; (void)out_size;
  const float* x   = (const float*)d_in[0];
  const float* lng = (const float*)d_in[1];
  const float* lnb = (const float*)d_in[2];
  const float* w1  = (const float*)d_in[3];
  const float* b1  = (const float*)d_in[4];
  const float* dw  = (const float*)d_in[5];
  const float* bdw = (const float*)d_in[6];
  const float* w2  = (const float*)d_in[7];
  const float* b2  = (const float*)d_in[8];
  const float* wg  = (const float*)d_in[9];
  const float* bg  = (const float*)d_in[10];
  float* out = (float*)d_out;

  char* ws = (char*)d_ws;
  size_t off_ = 0;
  auto carve = [&](size_t bytes) -> void* {
    void* p = ws + off_;
    off_ = (off_ + bytes + 255) & ~(size_t)255;
    return p;
  };
  short* w1p  = (short*)carve((size_t)NEXP*INNER*DIMC*2);
  float* b1p  = (float*)carve((size_t)NEXP*INNER*4);
  short* w2b  = (short*)carve((size_t)NEXP*DIMC*INNER*2);
  short* dwT  = (short*)carve((size_t)NEXP*9*INNER*2);
  short* nx   = (short*)carve((size_t)NPIX*DIMC*2);
  int*   e01  = (int*)carve((size_t)NPIX*4);
  float2* w01 = (float2*)carve((size_t)NPIX*8);
  int*   j0a  = (int*)carve((size_t)NPIX*4);
  int*   j1a  = (int*)carve((size_t)NPIX*4);
  int*   pix  = (int*)carve((size_t)MAXROWS*4);
  int*   cnt  = (int*)carve(2048*4);
  int*   seg  = (int*)carve(32*4);
  short* gTc  = (short*)carve((size_t)MAXROWS*INNER*2);
  float* Oc   = (float*)carve((size_t)MAXROWS*DIMC*4);

  // ec=4: two balanced rounds; per-round h (~101MB) + nx + gTc writes < L3
  const size_t per_e = (size_t)INNER*NPIX*2;
  size_t rem = (ws_size > off_) ? (ws_size - off_) : 0;
  int ec = (int)(rem / per_e);
  if (ec > 4) ec = 4;
  if (ec < 1) ec = 1;
  short* hbuf = (short*)(ws + off_);

  k_init<<<dim3(256 + 6144 + 1152 + 216), 256, 0, stream>>>(
      x, wg, bg, w1, b1, lng, lnb, w2, dw,
      nx, e01, w01, cnt, w1p, b1p, w2b, dwT);
  k_route3<<<dim3(64), 256, 0, stream>>>(e01, cnt, j0a, j1a, pix, seg);

  for (int eb = 0; eb < NEXP; eb += ec) {
    int ne = (eb + ec <= NEXP) ? ec : (NEXP - eb);
    k_up<<<dim3(NPIX/256, INNER/128, ne), 512, 0, stream>>>(w1p, b1p, nx, hbuf, eb);
    k_dws<<<dim3(MAXROWS/16, 3), 256, 0, stream>>>(hbuf, dwT, bdw, pix, seg,
                                                   gTc, eb, ne);
  }
  k_down<<<dim3(MAXROWS/128, DIMC/64), 256, 0, stream>>>(w2b, b2, gTc, seg, Oc);
  k_gather<<<dim3(NPIX/256), 256, 0, stream>>>(Oc, j0a, j1a, w01, out);
}

// Round 17
// 190.286 us; speedup vs baseline: 1.0116x; 1.0116x over previous
//
#include <hip/hip_runtime.h>
#include <math.h>

#define DIMC 192
#define INNER 768
#define NEXP 8
#define NB 4
#define HH 64
#define WW 64
#define PPI 4096
#define NPIX 16384
#define MAXROWS 33792   // 264 * 128

typedef __attribute__((ext_vector_type(8))) short bf16x8;
typedef __attribute__((ext_vector_type(4))) float f32x4;

static __device__ __forceinline__ float bf2f(short s) {
  union { unsigned int u; float f; } v;
  v.u = ((unsigned int)(unsigned short)s) << 16;
  return v.f;
}
static __device__ __forceinline__ float bfLO(unsigned int u) {
  union { unsigned int u; float f; } v; v.u = u << 16; return v.f;
}
static __device__ __forceinline__ float bfHI(unsigned int u) {
  union { unsigned int u; float f; } v; v.u = u & 0xffff0000u; return v.f;
}
static __device__ __forceinline__ short f2bf(float f) {
  union { float f; unsigned int u; } v; v.f = f;
  unsigned int r = v.u + 0x7fffu + ((v.u >> 16) & 1u);
  return (short)(r >> 16);
}
static __device__ __forceinline__ unsigned int pk2(float a, float b) {
  return (unsigned int)(unsigned short)f2bf(a)
       | ((unsigned int)(unsigned short)f2bf(b) << 16);
}
static __device__ __forceinline__ void gl2lds16(const void* g, void* l) {
  __builtin_amdgcn_global_load_lds(
      (const __attribute__((address_space(1))) void*)g,
      (__attribute__((address_space(3))) void*)l, 16, 0, 0);
}

// ==== merged init: gate+LN | w1-fold | w2-cast | dwT transpose ===============
// bid [0,256): gate (1 chunk of 64 px each); [256,6400): w1p/b1p;
// [6400,7552): w2b; [7552,7768): dwT
__global__ __launch_bounds__(256) void k_init(const float* __restrict__ x,
                                              const float* __restrict__ wg,
                                              const float* __restrict__ bg,
                                              const float* __restrict__ w1,
                                              const float* __restrict__ b1,
                                              const float* __restrict__ lng,
                                              const float* __restrict__ lnb,
                                              const float* __restrict__ w2,
                                              const float* __restrict__ dw,
                                              short* __restrict__ nx,
                                              int* __restrict__ e01,
                                              float2* __restrict__ w01,
                                              int* __restrict__ cnt,
                                              short* __restrict__ w1p,
                                              float* __restrict__ b1p,
                                              short* __restrict__ w2b,
                                              short* __restrict__ dwT) {
  __shared__ float swg[NEXP][DIMC];
  __shared__ float sbg[NEXP];
  __shared__ float red[10][4][64];
  __shared__ float smr[2][64];
  __shared__ float part[4];
  const int bid = blockIdx.x;
  const int t = threadIdx.x;
  if (bid < 256) {
    // ---- gate + layernorm for 64 pixels ----
    const int gb = bid;
    for (int k = t; k < NEXP*DIMC; k += 256) swg[k/DIMC][k%DIMC] = wg[k];
    if (t < NEXP) sbg[t] = bg[t];
    __syncthreads();
    const int n0 = gb * 64;
    const int b = n0 >> 12;
    const int p0 = n0 & 4095;
    const int l = t & 63, w = t >> 6;
    const float* xp = x + (size_t)b*DIMC*PPI + p0 + l;
    float xr[48];
    float sum = 0.f, ssq = 0.f;
    float lg[NEXP] = {0,0,0,0,0,0,0,0};
    #pragma unroll
    for (int k = 0; k < 48; ++k) {
      const int c = w*48 + k;
      float xv = xp[(size_t)c*PPI];
      xr[k] = xv;
      sum += xv; ssq += xv*xv;
      #pragma unroll
      for (int e = 0; e < NEXP; ++e) lg[e] += xv * swg[e][c];
    }
    red[0][w][l] = sum;
    red[1][w][l] = ssq;
    #pragma unroll
    for (int e = 0; e < NEXP; ++e) red[2+e][w][l] = lg[e];
    __syncthreads();
    if (t < 64) {
      float ts = red[0][0][l] + red[0][1][l] + red[0][2][l] + red[0][3][l];
      float tq = red[1][0][l] + red[1][1][l] + red[1][2][l] + red[1][3][l];
      float lgt[NEXP];
      #pragma unroll
      for (int e = 0; e < NEXP; ++e)
        lgt[e] = red[2+e][0][l] + red[2+e][1][l] + red[2+e][2][l] + red[2+e][3][l] + sbg[e];
      const float mean = ts * (1.0f/DIMC);
      const float var  = tq * (1.0f/DIMC) - mean*mean;
      const float rstd = rsqrtf(var + 1e-5f);
      smr[0][l] = mean; smr[1][l] = rstd;
      int e0 = 0; float l0 = lgt[0];
      #pragma unroll
      for (int e = 1; e < NEXP; ++e) if (lgt[e] > l0) { l0 = lgt[e]; e0 = e; }
      int e1 = -1; float l1 = -1e30f;
      #pragma unroll
      for (int e = 0; e < NEXP; ++e) if (e != e0 && lgt[e] > l1) { l1 = lgt[e]; e1 = e; }
      const float ex = expf(l1 - l0);
      const float w0 = 1.0f/(1.0f + ex);
      const float w1v = ex * w0;
      e01[n0 + l] = e0 | (e1 << 8);
      w01[n0 + l] = make_float2(w0, w1v);
      #pragma unroll
      for (int e = 0; e < NEXP; ++e) {
        unsigned long long m = __ballot(e0 == e || e1 == e);
        if (l == 0) cnt[e*256 + gb] = (int)__popcll(m);
      }
    }
    __syncthreads();
    const float mean = smr[0][l], rstd = smr[1][l];
    short* nrow = nx + (size_t)(n0 + l)*DIMC + w*48;
    #pragma unroll
    for (int q = 0; q < 6; ++q) {
      bf16x8 v;
      #pragma unroll
      for (int j = 0; j < 8; ++j)
        v[j] = f2bf((xr[q*8 + j] - mean) * rstd);
      *(bf16x8*)(nrow + q*8) = v;
    }
  } else if (bid < 6400) {
    // ---- w1 fold ----
    const int r = bid - 256;
    const int e = r / 768, i = r - e*768;
    const size_t base = ((size_t)e*INNER + i)*DIMC;
    float rr = 0.f;
    if (t < DIMC) {
      const float w = w1[base + t];
      w1p[base + t] = f2bf(w * lng[e*DIMC + t]);
      rr = w * lnb[e*DIMC + t];
    }
    #pragma unroll
    for (int off = 32; off >= 1; off >>= 1) rr += __shfl_down(rr, off);
    const int lane = t & 63, wv = t >> 6;
    if (lane == 0) part[wv] = rr;
    __syncthreads();
    if (t == 0)
      b1p[e*INNER + i] = b1[e*INNER + i] + part[0] + part[1] + part[2];
  } else if (bid < 7552) {
    // ---- w2 cast ----
    const int n = NEXP*DIMC*INNER;
    int idx = ((bid - 6400)*256 + t)*4;
    if (idx + 3 < n) {
      float4 v = *(const float4*)(w2 + idx);
      short4 o; o.x = f2bf(v.x); o.y = f2bf(v.y); o.z = f2bf(v.z); o.w = f2bf(v.w);
      *(short4*)(w2b + idx) = o;
    } else {
      for (int k = idx; k < n; ++k) w2b[k] = f2bf(w2[k]);
    }
  } else {
    // ---- dwT transpose ----
    const int r = bid - 7552;                 // ((e*9)+q)*3 + cb
    const int cb = r % 3, qq = (r/3) % 9, e = r / 27;
    const int c = cb*256 + t;
    dwT[((size_t)e*9 + qq)*INNER + c] = f2bf(dw[((size_t)e*INNER + c)*9 + qq]);
  }
}

// -- routing: per-block redundant 256-chunk scan of cnt -> slots/pix/seg ------
__global__ __launch_bounds__(256) void k_route3(const int* __restrict__ e01,
                                                const int* __restrict__ cnt,
                                                int* __restrict__ j0a,
                                                int* __restrict__ j1a,
                                                int* __restrict__ pix,
                                                int* __restrict__ seg) {
  __shared__ int wc[NEXP][4];
  __shared__ int sOff[NEXP];    // exclusive chunk-prefix at chunk 4*bx
  __shared__ int sTot[NEXP];    // per-expert totals
  __shared__ int sSt[NEXP];     // segment starts
  const int t = threadIdx.x;
  const int bx = blockIdx.x;
  const int lane = t & 63, wv = t >> 6;
  const int n = bx*256 + t;
  const int ee = e01[n];
  const int e0 = ee & 0xff, e1 = (ee >> 8) & 0xff;
  unsigned long long masks[NEXP];
  #pragma unroll
  for (int e = 0; e < NEXP; ++e) {
    unsigned long long m = __ballot(e0 == e || e1 == e);
    if (lane == 0) wc[e][wv] = __popcll(m);
    masks[e] = m;
  }
  // wave wv scans experts 2wv, 2wv+1 over 256 chunks (4 x 64 with carry)
  #pragma unroll
  for (int s = 0; s < 2; ++s) {
    const int e = wv*2 + s;
    int carry = 0;
    #pragma unroll
    for (int q4 = 0; q4 < 4; ++q4) {
      const int v = cnt[e*256 + q4*64 + lane];
      int sc = v;
      #pragma unroll
      for (int d = 1; d < 64; d <<= 1) {
        int u = __shfl_up(sc, d);
        if (lane >= d) sc += u;
      }
      if (q4*64 + lane == (bx << 2)) sOff[e] = carry + sc - v;
      carry += __shfl(sc, 63);
    }
    if (lane == 0) sTot[e] = carry;
  }
  __syncthreads();
  if (t == 0) {
    int run = 0;
    #pragma unroll
    for (int q = 0; q < NEXP; ++q) {
      const int m = sTot[q];
      const int pad = (m + 127) & ~127;
      sSt[q] = run;
      if (bx == 0) {
        seg[q*3 + 0] = run;
        seg[q*3 + 1] = m;
        seg[q*3 + 2] = run + pad;
      }
      run += pad;
    }
    if (bx == 0) seg[24] = run;
  }
  __syncthreads();
  int j0 = 0, j1 = 0;
  #pragma unroll
  for (int e = 0; e < NEXP; ++e) {
    int base = sSt[e] + sOff[e];
    #pragma unroll
    for (int w = 0; w < 4; ++w) if (w < wv) base += wc[e][w];
    int rank = __popcll(masks[e] & ((1ull << lane) - 1ull));
    bool sel = (e0 == e || e1 == e);
    int j = base + rank;
    if (sel) pix[j] = n;
    if (e == e0) j0 = j;
    if (e == e1) j1 = j;
  }
  j0a[n] = j0; j1a[n] = j1;
}

// ------- up-projection GEMM: 128x128, BK=64, XOR-swizzled LDS;
// ------- epilogue: LDS transpose -> hT[n][768] coalesced 16B stores ----------
__global__ __launch_bounds__(256) void k_up(const short* __restrict__ w1p,
                                            const float* __restrict__ b1p,
                                            const short* __restrict__ nx,
                                            short* __restrict__ hbuf, int eb) {
  __shared__ alignas(16) short smemU[128*136];   // As|Bs during GEMM, TT after
  short* As = smemU;
  short* Bs = smemU + 128*64;
  const int el = blockIdx.z;
  const int e = eb + el;
  const short* A = w1p + (size_t)e*INNER*DIMC;
  short* H = hbuf + (size_t)el*NPIX*INNER;      // hT layout [n][768]
  const int n0 = blockIdx.x << 7;
  const int i0 = blockIdx.y << 7;
  const int t = threadIdx.x;
  const int wv = t >> 6, lane = t & 63;
  const int wm = (wv & 1) << 6;
  const int wn = (wv >> 1) << 6;
  const int r15 = lane & 15, kg = lane >> 4;
  f32x4 acc[4][4] = {};
  for (int k0 = 0; k0 < DIMC; k0 += 64) {
    __syncthreads();
    #pragma unroll
    for (int q = 0; q < 4; ++q) {
      const int c = q*256 + t;
      const int row = c >> 3;
      const int kb = ((c & 7) << 4) ^ ((row & 7) << 4);   // pre-swizzled source
      gl2lds16(A + (size_t)(i0 + row)*DIMC + k0 + (kb >> 1), (char*)As + c*16);
      gl2lds16(nx + (size_t)(n0 + row)*DIMC + k0 + (kb >> 1), (char*)Bs + c*16);
    }
    __syncthreads();
    #pragma unroll
    for (int ks = 0; ks < 2; ++ks) {
      bf16x8 af[4], bfr[4];
      #pragma unroll
      for (int mf = 0; mf < 4; ++mf) {
        const int row = wm + mf*16 + r15;
        const int kb = (ks*64 + kg*16) ^ ((row & 7) << 4);
        af[mf] = *(const bf16x8*)((const char*)As + row*128 + kb);
      }
      #pragma unroll
      for (int nf = 0; nf < 4; ++nf) {
        const int row = wn + nf*16 + r15;
        const int kb = (ks*64 + kg*16) ^ ((row & 7) << 4);
        bfr[nf] = *(const bf16x8*)((const char*)Bs + row*128 + kb);
      }
      #pragma unroll
      for (int mf = 0; mf < 4; ++mf)
        #pragma unroll
        for (int nf = 0; nf < 4; ++nf)
          acc[mf][nf] = __builtin_amdgcn_mfma_f32_16x16x32_bf16(af[mf], bfr[nf], acc[mf][nf], 0, 0, 0);
    }
  }
  // epilogue: acc(+bias) -> TT[n_l][i_l] (stride 136 shorts, 16B-aligned rows)
  __syncthreads();
  unsigned int* TT32 = (unsigned int*)smemU;
  const float* b1e = b1p + e*INNER + i0;
  #pragma unroll
  for (int mf = 0; mf < 4; ++mf) {
    const int ib = wm + mf*16 + (kg << 2);
    float bias[4];
    #pragma unroll
    for (int r = 0; r < 4; ++r) bias[r] = b1e[ib + r];
    #pragma unroll
    for (int nf = 0; nf < 4; ++nf) {
      const int nl = wn + nf*16 + r15;
      TT32[nl*68 + (ib >> 1)]     = pk2(acc[mf][nf][0] + bias[0], acc[mf][nf][1] + bias[1]);
      TT32[nl*68 + (ib >> 1) + 1] = pk2(acc[mf][nf][2] + bias[2], acc[mf][nf][3] + bias[3]);
    }
  }
  __syncthreads();
  const short* TT = smemU;
  #pragma unroll
  for (int s = 0; s < 8; ++s) {
    const int idx = (s << 8) + t;
    const int nl = idx >> 4, cg = idx & 15;
    bf16x8 v = *(const bf16x8*)(TT + nl*136 + cg*8);
    *(bf16x8*)(H + (size_t)(n0 + nl)*INNER + i0 + cg*8) = v;
  }
}

// ------- sparse depthwise 3x3 + GELU; thread = 4 slots x 4 channels ----------
// bf16 packed weights (9x8B regs); pad slots write zeros
__global__ __launch_bounds__(256) void k_dws(const short* __restrict__ hbuf,
                                             const short* __restrict__ dwT,
                                             const float* __restrict__ bdw,
                                             const int* __restrict__ pix,
                                             const int* __restrict__ seg,
                                             short* __restrict__ gTc,
                                             int eb, int ne) {
  const int j0 = blockIdx.x << 4;     // 16 slots per block (16 | 128 -> one expert)
  if (j0 >= seg[24]) return;
  int e = 0;
  #pragma unroll
  for (int q = 0; q < NEXP; ++q)
    if (j0 >= seg[q*3] && j0 < seg[q*3+2]) e = q;
  if (e < eb || e >= eb + ne) return;
  const int jend = seg[e*3] + seg[e*3+1];
  const int t = threadIdx.x;
  const int cq = t & 63;              // 64 ch-quads = 256 channels
  const int sq = t >> 6;              // 4 slot-quads
  const int ch = (blockIdx.y << 8) + (cq << 2);
  const short* hb = hbuf + (size_t)(e - eb)*NPIX*INNER;
  uint2 wq[9];
  #pragma unroll
  for (int q = 0; q < 9; ++q)
    wq[q] = *(const uint2*)(dwT + ((size_t)e*9 + q)*INNER + ch);
  const float4 bias = *(const float4*)(bdw + (size_t)e*INNER + ch);
  #pragma unroll
  for (int s = 0; s < 4; ++s) {
    const int j = j0 + (sq << 2) + s;
    if (j >= jend) {                  // padding slot: zero
      uint2 z; z.x = 0u; z.y = 0u;
      *(uint2*)(gTc + (size_t)j*INNER + ch) = z;
      continue;
    }
    const int n = pix[j];
    const int p = n & 4095, y = p >> 6, x = p & 63;
    uint2 v[9];
    #pragma unroll
    for (int dy = -1; dy <= 1; ++dy)
      #pragma unroll
      for (int dx = -1; dx <= 1; ++dx) {
        uint2 z; z.x = 0u; z.y = 0u;
        if ((unsigned)(y + dy) < 64u && (unsigned)(x + dx) < 64u)
          z = *(const uint2*)(hb + (size_t)(n + dy*64 + dx)*INNER + ch);
        v[(dy+1)*3 + dx + 1] = z;
      }
    float a0 = bias.x, a1 = bias.y, a2 = bias.z, a3 = bias.w;
    #pragma unroll
    for (int q = 0; q < 9; ++q) {
      a0 += bfLO(wq[q].x) * bfLO(v[q].x);
      a1 += bfHI(wq[q].x) * bfHI(v[q].x);
      a2 += bfLO(wq[q].y) * bfLO(v[q].y);
      a3 += bfHI(wq[q].y) * bfHI(v[q].y);
    }
    const float g0 = 0.5f*a0*(1.0f + erff(a0*0.70710678118654752f));
    const float g1 = 0.5f*a1*(1.0f + erff(a1*0.70710678118654752f));
    const float g2 = 0.5f*a2*(1.0f + erff(a2*0.70710678118654752f));
    const float g3 = 0.5f*a3*(1.0f + erff(a3*0.70710678118654752f));
    uint2 o; o.x = pk2(g0, g1); o.y = pk2(g2, g3);
    *(uint2*)(gTc + (size_t)j*INNER + ch) = o;
  }
}

// ------- down-projection GEMM: 128j x 64c tile, BK=64, swizzled LDS ----------
__global__ __launch_bounds__(256) void k_down(const short* __restrict__ w2b,
                                              const float* __restrict__ b2,
                                              const short* __restrict__ gTc,
                                              const int* __restrict__ seg,
                                              float* __restrict__ Oc) {
  __shared__ alignas(16) short As[64*64];    // [c][k64], XOR-swizzled
  __shared__ alignas(16) short Bs[128*64];   // [j][k64], XOR-swizzled
  __shared__ float sb2[64];
  const int j0g = blockIdx.x << 7;
  if (j0g >= seg[24]) return;
  int e = 0;
  #pragma unroll
  for (int q = 0; q < NEXP; ++q)
    if (j0g >= seg[q*3] && j0g < seg[q*3+2]) e = q;
  const int c0 = blockIdx.y << 6;
  const short* A = w2b + (size_t)e*DIMC*INNER;
  const short* B = gTc + (size_t)j0g*INNER;
  const int t = threadIdx.x;
  const int wv = t >> 6, lane = t & 63;
  const int wc_ = (wv & 1) << 5;   // c-offset of wave
  const int wj  = (wv >> 1) << 6;  // j-offset of wave
  const int r15 = lane & 15, kg = lane >> 4;
  if (t < 64) sb2[t] = b2[e*DIMC + c0 + t];
  f32x4 acc[2][4] = {};
  for (int k0 = 0; k0 < INNER; k0 += 64) {
    __syncthreads();
    #pragma unroll
    for (int q = 0; q < 2; ++q) {              // A: 64 rows x 128B
      const int c = q*256 + t;
      const int row = c >> 3;
      const int kb = ((c & 7) << 4) ^ ((row & 7) << 4);
      gl2lds16(A + (size_t)(c0 + row)*INNER + k0 + (kb >> 1), (char*)As + c*16);
    }
    #pragma unroll
    for (int q = 0; q < 4; ++q) {              // B: 128 rows x 128B
      const int c = q*256 + t;
      const int row = c >> 3;
      const int kb = ((c & 7) << 4) ^ ((row & 7) << 4);
      gl2lds16(B + (size_t)row*INNER + k0 + (kb >> 1), (char*)Bs + c*16);
    }
    __syncthreads();
    #pragma unroll
    for (int ks = 0; ks < 2; ++ks) {
      bf16x8 af[2], bfr[4];
      #pragma unroll
      for (int mf = 0; mf < 2; ++mf) {
        const int row = wc_ + mf*16 + r15;
        const int kb = (ks*64 + kg*16) ^ ((row & 7) << 4);
        af[mf] = *(const bf16x8*)((const char*)As + row*128 + kb);
      }
      #pragma unroll
      for (int nf = 0; nf < 4; ++nf) {
        const int row = wj + nf*16 + r15;
        const int kb = (ks*64 + kg*16) ^ ((row & 7) << 4);
        bfr[nf] = *(const bf16x8*)((const char*)Bs + row*128 + kb);
      }
      #pragma unroll
      for (int mf = 0; mf < 2; ++mf)
        #pragma unroll
        for (int nf = 0; nf < 4; ++nf)
          acc[mf][nf] = __builtin_amdgcn_mfma_f32_16x16x32_bf16(af[mf], bfr[nf], acc[mf][nf], 0, 0, 0);
    }
  }
  #pragma unroll
  for (int mf = 0; mf < 2; ++mf) {
    const int ccl = wc_ + mf*16 + (kg << 2);
    #pragma unroll
    for (int nf = 0; nf < 4; ++nf) {
      const int jj = j0g + wj + nf*16 + r15;
      float4 v;
      v.x = acc[mf][nf][0] + sb2[ccl + 0];
      v.y = acc[mf][nf][1] + sb2[ccl + 1];
      v.z = acc[mf][nf][2] + sb2[ccl + 2];
      v.w = acc[mf][nf][3] + sb2[ccl + 3];
      *(float4*)(Oc + (size_t)jj*DIMC + c0 + ccl) = v;
    }
  }
}

// ---------------- final gather: out = w0*Oc[j0] + w1*Oc[j1] ------------------
__global__ __launch_bounds__(256) void k_gather(const float* __restrict__ Oc,
                                                const int* __restrict__ j0a,
                                                const int* __restrict__ j1a,
                                                const float2* __restrict__ w01,
                                                float* __restrict__ out) {
  const int t = threadIdx.x;
  const int n = blockIdx.x*256 + t;
  const int b = n >> 12, p = n & 4095;
  const int j0 = j0a[n], j1 = j1a[n];
  const float2 w = w01[n];
  const float4* r0 = (const float4*)(Oc + (size_t)j0*DIMC);
  const float4* r1 = (const float4*)(Oc + (size_t)j1*DIMC);
  float* ob = out + (size_t)b*DIMC*PPI + p;
  for (int cq = 0; cq < 48; ++cq) {
    float4 a = r0[cq], c = r1[cq];
    ob[(size_t)(cq*4 + 0)*PPI] = w.x*a.x + w.y*c.x;
    ob[(size_t)(cq*4 + 1)*PPI] = w.x*a.y + w.y*c.y;
    ob[(size_t)(cq*4 + 2)*PPI] = w.x*a.z + w.y*c.z;
    ob[(size_t)(cq*4 + 3)*PPI] = w.x*a.w + w.y*c.w;
  }
}

extern "C" void kernel_launch(void* const* d_in, const int* in_sizes, int n_in,
                              void* d_out, int out_size, void* d_ws, size_t ws_size,
                              hipStream_t stream) {
  (void)in_sizes; (void)n_in; (void)out_size;
  const float* x   = (const float*)d_in[0];
  const float* lng = (const float*)d_in[1];
  const float* lnb = (const float*)d_in[2];
  const float* w1  = (const float*)d_in[3];
  const float* b1  = (const float*)d_in[4];
  const float* dw  = (const float*)d_in[5];
  const float* bdw = (const float*)d_in[6];
  const float* w2  = (const float*)d_in[7];
  const float* b2  = (const float*)d_in[8];
  const float* wg  = (const float*)d_in[9];
  const float* bg  = (const float*)d_in[10];
  float* out = (float*)d_out;

  char* ws = (char*)d_ws;
  size_t off_ = 0;
  auto carve = [&](size_t bytes) -> void* {
    void* p = ws + off_;
    off_ = (off_ + bytes + 255) & ~(size_t)255;
    return p;
  };
  short* w1p  = (short*)carve((size_t)NEXP*INNER*DIMC*2);
  float* b1p  = (float*)carve((size_t)NEXP*INNER*4);
  short* w2b  = (short*)carve((size_t)NEXP*DIMC*INNER*2);
  short* dwT  = (short*)carve((size_t)NEXP*9*INNER*2);
  short* nx   = (short*)carve((size_t)NPIX*DIMC*2);
  int*   e01  = (int*)carve((size_t)NPIX*4);
  float2* w01 = (float2*)carve((size_t)NPIX*8);
  int*   j0a  = (int*)carve((size_t)NPIX*4);
  int*   j1a  = (int*)carve((size_t)NPIX*4);
  int*   pix  = (int*)carve((size_t)MAXROWS*4);
  int*   cnt  = (int*)carve(2048*4);
  int*   seg  = (int*)carve(32*4);
  short* gTc  = (short*)carve((size_t)MAXROWS*INNER*2);
  float* Oc   = (float*)carve((size_t)MAXROWS*DIMC*4);

  // ec=4: two balanced rounds; per-round h (~101MB) + nx + gTc writes < L3
  const size_t per_e = (size_t)INNER*NPIX*2;
  size_t rem = (ws_size > off_) ? (ws_size - off_) : 0;
  int ec = (int)(rem / per_e);
  if (ec > 4) ec = 4;
  if (ec < 1) ec = 1;
  short* hbuf = (short*)(ws + off_);

  k_init<<<dim3(256 + 6144 + 1152 + 216), 256, 0, stream>>>(
      x, wg, bg, w1, b1, lng, lnb, w2, dw,
      nx, e01, w01, cnt, w1p, b1p, w2b, dwT);
  k_route3<<<dim3(64), 256, 0, stream>>>(e01, cnt, j0a, j1a, pix, seg);

  for (int eb = 0; eb < NEXP; eb += ec) {
    int ne = (eb + ec <= NEXP) ? ec : (NEXP - eb);
    k_up<<<dim3(NPIX/128, INNER/128, ne), 256, 0, stream>>>(w1p, b1p, nx, hbuf, eb);
    k_dws<<<dim3(MAXROWS/16, 3), 256, 0, stream>>>(hbuf, dwT, bdw, pix, seg,
                                                   gTc, eb, ne);
  }
  k_down<<<dim3(MAXROWS/128, DIMC/64), 256, 0, stream>>>(w2b, b2, gTc, seg, Oc);
  k_gather<<<dim3(NPIX/256), 256, 0, stream>>>(Oc, j0a, j1a, w01, out);
}